// Round 1
// baseline (3965.809 us; speedup 1.0000x reference)
//
#include <hip/hip_runtime.h>
#include <math.h>

// Semantic predictor: fused transformer (N samples x V=6 tokens x DIM=32, 4 layers)
// + MLP head (192->192->96->20), all fp32.
// Thread = (sample, token-row v). 6 lanes per sample, 10 samples per wave (lanes 60-63 idle).
// Weights staged in LDS (broadcast float4 reads). Activation rows live in registers;
// rolled-k matmuls re-read the own row from a stride-33 LDS buffer (<=2-way bank alias = free).
// Attention k/v row exchange via __shfl within the wave. Softmax/LN thread-local.

#define BLOCK 256
#define SPW   10          // samples per wave
#define SPB   40          // samples per block (4 waves)
#define ASTR  33          // activation row stride (bank-conflict-free)
#define WBF   6944        // LDS weight staging buffer (floats)
#define ABF   7920        // 240 rows * 33
#define ATTN_SCALE 0.35355339059327373f  // 1/sqrt(8)

__device__ __forceinline__ float elu_f(float x) { return x > 0.f ? x : expm1f(x); }

__device__ __forceinline__ void fma_row32(float* acc, const float* wrow, float a) {
  const float4* wr = (const float4*)wrow;
#pragma unroll
  for (int jj = 0; jj < 8; ++jj) {
    float4 w = wr[jj];
    acc[4*jj+0] += a * w.x; acc[4*jj+1] += a * w.y;
    acc[4*jj+2] += a * w.z; acc[4*jj+3] += a * w.w;
  }
}

__device__ __forceinline__ void matmul32(float* acc, const float* wlds, const float* arow) {
#pragma unroll 4
  for (int k2 = 0; k2 < 32; ++k2) {
    fma_row32(acc, wlds + k2*32, arow[k2]);
  }
}

__device__ __forceinline__ void lnorm32(float* x, const float* g, const float* b) {
  float m = 0.f;
#pragma unroll
  for (int d = 0; d < 32; ++d) m += x[d];
  m *= 0.03125f;
  float var = 0.f;
#pragma unroll
  for (int d = 0; d < 32; ++d) { float c = x[d] - m; var += c * c; }
  var *= 0.03125f;
  float r = 1.f / sqrtf(var + 1e-6f);
#pragma unroll
  for (int d = 0; d < 32; ++d) x[d] = (x[d] - m) * r * g[d] + b[d];
}

__global__ __launch_bounds__(BLOCK, 2)
void sem_kernel(const float* __restrict__ feat, const float* __restrict__ occ,
                const float* __restrict__ tokw, const float* __restrict__ tokb,
                const float* __restrict__ wq,   const float* __restrict__ wk,
                const float* __restrict__ wvm,  const float* __restrict__ wo,
                const float* __restrict__ ln1g, const float* __restrict__ ln1b,
                const float* __restrict__ fw1,  const float* __restrict__ fb1,
                const float* __restrict__ fw2,  const float* __restrict__ fb2,
                const float* __restrict__ ln2g, const float* __restrict__ ln2b,
                const float* __restrict__ fc1w, const float* __restrict__ fc1b,
                const float* __restrict__ fc2w, const float* __restrict__ fc2b,
                const float* __restrict__ fc3w, const float* __restrict__ fc3b,
                float* __restrict__ outp, int ntot)
{
  __shared__ float wbuf[WBF];
  __shared__ float abuf[ABF];

  const int tid  = threadIdx.x;
  const int lane = tid & 63;
  const int wid  = tid >> 6;
  const int siw  = lane / 6;              // 0..10 (10 => idle lane 60-63)
  const int v    = lane - siw * 6;        // 0..5
  const bool alane = (siw < SPW);
  const int slocal = wid * SPW + (alane ? siw : 0);
  const int n    = blockIdx.x * SPB + slocal;
  const bool act = alane && (n < ntot);
  const int rowoff = (slocal * 6 + v) * ASTR;
  const int sbase  = siw * 6;             // shuffle base lane of this sample

  auto cp4 = [&](int dst, const float* __restrict__ src, int nf) {
    float4* d4 = (float4*)(wbuf + dst);
    const float4* s4 = (const float4*)src;
    for (int i = tid; i < (nf >> 2); i += BLOCK) d4[i] = s4[i];
  };

  // ---------------- masks (each of the 6 lanes computes its sample's mask) -------------
  float vr[6], mc[6], msk[6];
#pragma unroll
  for (int u = 0; u < 6; ++u) vr[u] = act ? feat[(n*6 + u)*48 + 47] : 0.f;
  float s0 = vr[0]+vr[1]+vr[2]+vr[3]+vr[4]+vr[5];
#pragma unroll
  for (int u = 0; u < 6; ++u) { vr[u] = (s0 == 0.f) ? 1.f : vr[u]; mc[u] = vr[u]; }
#pragma unroll
  for (int u = 0; u < 6; ++u) vr[u] *= act ? occ[n*6 + u] : 0.f;
  float s2 = vr[0]+vr[1]+vr[2]+vr[3]+vr[4]+vr[5];
#pragma unroll
  for (int u = 0; u < 6; ++u) msk[u] = ((s2 == 0.f) ? 1.f : vr[u]) * mc[u];

  // ---------------- token embedding ----------------
  cp4(0, tokw, 672);
  cp4(672, tokb, 32);
  __syncthreads();

  float in21[21];
  {
    float4 sf0, sf1, sf2, sf3, sf4; float visr;
    if (act) {
      const float* fb = feat + (n*6 + v)*48;
      const float4* fp = (const float4*)(fb + 24);
      sf0 = fp[0]; sf1 = fp[1]; sf2 = fp[2]; sf3 = fp[3]; sf4 = fp[4];
      visr = fb[47];
    } else {
      sf0 = sf1 = sf2 = sf3 = sf4 = make_float4(0.f, 0.f, 0.f, 0.f); visr = 0.f;
    }
    in21[0]  = visr;
    in21[1]  = sf0.x; in21[2]  = sf0.y; in21[3]  = sf0.z; in21[4]  = sf0.w;
    in21[5]  = sf1.x; in21[6]  = sf1.y; in21[7]  = sf1.z; in21[8]  = sf1.w;
    in21[9]  = sf2.x; in21[10] = sf2.y; in21[11] = sf2.z; in21[12] = sf2.w;
    in21[13] = sf3.x; in21[14] = sf3.y; in21[15] = sf3.z; in21[16] = sf3.w;
    in21[17] = sf4.x; in21[18] = sf4.y; in21[19] = sf4.z; in21[20] = sf4.w;
  }

  float res[32];   // this thread's token row (registers)
  {
    float acc[32];
#pragma unroll
    for (int d = 0; d < 32; ++d) acc[d] = wbuf[672 + d];
#pragma unroll
    for (int j = 0; j < 21; ++j) {
      fma_row32(acc, &wbuf[j*32], in21[j]);
    }
#pragma unroll
    for (int d = 0; d < 32; ++d) res[d] = elu_f(acc[d]);
    if (alane) {
#pragma unroll
      for (int d = 0; d < 32; ++d) abuf[rowoff + d] = res[d];
    }
  }

  // ---------------- transformer layers ----------------
  for (int l = 0; l < 4; ++l) {
    __syncthreads();
    cp4(0,    wq  + l*1024, 1024);
    cp4(1024, wk  + l*1024, 1024);
    cp4(2048, wvm + l*1024, 1024);
    cp4(3072, wo  + l*1024, 1024);
    cp4(4096, fw1 + l*1024, 1024);
    cp4(5120, fw2 + l*1024, 1024);
    cp4(6144, ln1g + l*32, 32);
    cp4(6176, ln1b + l*32, 32);
    cp4(6208, fb1  + l*32, 32);
    cp4(6240, fb2  + l*32, 32);
    cp4(6272, ln2g + l*32, 32);
    cp4(6304, ln2b + l*32, 32);
    __syncthreads();

    // fused q/k/v matmuls (input = own token row from abuf)
    float qr[32], kr[32], vrg[32];
#pragma unroll
    for (int d = 0; d < 32; ++d) { qr[d] = 0.f; kr[d] = 0.f; vrg[d] = 0.f; }
#pragma unroll 2
    for (int k2 = 0; k2 < 32; ++k2) {
      float a = abuf[rowoff + k2];
      fma_row32(qr,  &wbuf[        k2*32], a);
      fma_row32(kr,  &wbuf[1024 +  k2*32], a);
      fma_row32(vrg, &wbuf[2048 +  k2*32], a);
    }

    // attention scores: p[h][u], key rows via wave shuffle
    float p[4][6];
#pragma unroll
    for (int u = 0; u < 6; ++u) {
      float dh[4] = {0.f, 0.f, 0.f, 0.f};
#pragma unroll
      for (int j = 0; j < 32; ++j) {
        float ku = __shfl(kr[j], sbase + u, 64);
        dh[j >> 3] += qr[j] * ku;
      }
#pragma unroll
      for (int h = 0; h < 4; ++h)
        p[h][u] = (msk[u] == 0.f) ? -INFINITY : dh[h] * ATTN_SCALE;
    }
    // softmax per head (thread-local, 6 keys)
#pragma unroll
    for (int h = 0; h < 4; ++h) {
      float mx = p[h][0];
#pragma unroll
      for (int u = 1; u < 6; ++u) mx = fmaxf(mx, p[h][u]);
      float sum = 0.f;
#pragma unroll
      for (int u = 0; u < 6; ++u) { float e = __expf(p[h][u] - mx); p[h][u] = e; sum += e; }
      float inv = 1.f / sum;
#pragma unroll
      for (int u = 0; u < 6; ++u) p[h][u] *= inv;
    }
    // o = attn @ v, value rows via wave shuffle
    float o[32];
#pragma unroll
    for (int d = 0; d < 32; ++d) o[d] = 0.f;
#pragma unroll
    for (int u = 0; u < 6; ++u) {
#pragma unroll
      for (int j = 0; j < 32; ++j) {
        float vu = __shfl(vrg[j], sbase + u, 64);
        o[j] += p[j >> 3][u] * vu;
      }
    }
    if (alane) {
#pragma unroll
      for (int d = 0; d < 32; ++d) abuf[rowoff + d] = o[d];
    }

    // x = LN1(o @ wo + res)
    float x[32];
#pragma unroll
    for (int d = 0; d < 32; ++d) x[d] = res[d];
    matmul32(x, &wbuf[3072], &abuf[rowoff]);
    lnorm32(x, &wbuf[6144], &wbuf[6176]);
    if (alane) {
#pragma unroll
      for (int d = 0; d < 32; ++d) abuf[rowoff + d] = x[d];
    }

    // h = relu(x @ ffn_w1 + b1)
    float hh[32];
#pragma unroll
    for (int d = 0; d < 32; ++d) hh[d] = 0.f;
    matmul32(hh, &wbuf[4096], &abuf[rowoff]);
#pragma unroll
    for (int d = 0; d < 32; ++d) hh[d] = fmaxf(hh[d] + wbuf[6208 + d], 0.f);
    if (alane) {
#pragma unroll
      for (int d = 0; d < 32; ++d) abuf[rowoff + d] = hh[d];
    }

    // tokens = LN2(x + h @ ffn_w2 + b2)
    float f2[32];
#pragma unroll
    for (int d = 0; d < 32; ++d) f2[d] = 0.f;
    matmul32(f2, &wbuf[5120], &abuf[rowoff]);
#pragma unroll
    for (int d = 0; d < 32; ++d) f2[d] = x[d] + f2[d] + wbuf[6240 + d];
    lnorm32(f2, &wbuf[6272], &wbuf[6304]);
#pragma unroll
    for (int d = 0; d < 32; ++d) res[d] = f2[d];
    if (alane) {
#pragma unroll
      for (int d = 0; d < 32; ++d) abuf[rowoff + d] = res[d];
    }
  }

  // ---------------- head: fc1 (192x192), thread computes cols [v*32, v*32+32) ----------
  float acc1[32];
#pragma unroll
  for (int j = 0; j < 32; ++j) acc1[j] = fc1b[v*32 + j];
  for (int c = 0; c < 6; ++c) {
    __syncthreads();
    // stage fc1 rows [c*32, c*32+32) x 192 cols, column blocks padded to stride 36
    for (int idx = tid; idx < 6144; idx += BLOCK) {
      int kk = idx / 192, col = idx - kk*192;
      wbuf[kk*216 + (col >> 5)*36 + (col & 31)] = fc1w[(c*32 + kk)*192 + col];
    }
    __syncthreads();
    const int arow = (slocal*6 + c) * ASTR;
#pragma unroll 4
    for (int kk = 0; kk < 32; ++kk) {
      float a = abuf[arow + kk];
      fma_row32(acc1, &wbuf[kk*216 + v*36], a);
    }
  }
  __syncthreads();
  if (alane) {
#pragma unroll
    for (int j = 0; j < 32; ++j) abuf[slocal*193 + v*32 + j] = elu_f(acc1[j]);
  }

  // ---------------- fc2 (192x96), thread computes cols [v*16, v*16+16) ----------
  float acc2[16];
#pragma unroll
  for (int j = 0; j < 16; ++j) acc2[j] = fc2b[v*16 + j];
  for (int c = 0; c < 4; ++c) {
    __syncthreads();
    // stage fc2 rows [c*48, c*48+48) x 96 cols, 16-col blocks padded to stride 20
    for (int idx = tid; idx < 4608; idx += BLOCK) {
      int kk = idx / 96, col = idx - kk*96;
      wbuf[kk*120 + (col >> 4)*20 + (col & 15)] = fc2w[(c*48 + kk)*96 + col];
    }
    __syncthreads();
#pragma unroll 4
    for (int kk = 0; kk < 48; ++kk) {
      float a = abuf[slocal*193 + c*48 + kk];
      const float4* wr = (const float4*)&wbuf[kk*120 + v*20];
#pragma unroll
      for (int jj = 0; jj < 4; ++jj) {
        float4 w = wr[jj];
        acc2[4*jj+0] += a * w.x; acc2[4*jj+1] += a * w.y;
        acc2[4*jj+2] += a * w.z; acc2[4*jj+3] += a * w.w;
      }
    }
  }
  __syncthreads();
  if (alane) {
#pragma unroll
    for (int j = 0; j < 16; ++j) abuf[slocal*97 + v*16 + j] = elu_f(acc2[j]);
  }

  // ---------------- fc3 (96x20), threads v=0..4 compute 4 cols each ----------
  __syncthreads();
  cp4(0, fc3w, 1920);
  __syncthreads();
  {
    const int cb = (v < 5) ? v*4 : 0;
    float a3[4] = { fc3b[cb], fc3b[cb+1], fc3b[cb+2], fc3b[cb+3] };
#pragma unroll 8
    for (int kk = 0; kk < 96; ++kk) {
      float a = abuf[slocal*97 + kk];
      const float4* wr = (const float4*)&wbuf[kk*20 + cb];
      float4 w = *wr;
      a3[0] += a * w.x; a3[1] += a * w.y; a3[2] += a * w.z; a3[3] += a * w.w;
    }
    if (act && v < 5) {
#pragma unroll
      for (int j = 0; j < 4; ++j) outp[n*20 + cb + j] = fmaxf(a3[j], 0.f);
    }
  }
}

extern "C" void kernel_launch(void* const* d_in, const int* in_sizes, int n_in,
                              void* d_out, int out_size, void* d_ws, size_t ws_size,
                              hipStream_t stream)
{
  const float* feat = (const float*)d_in[0];
  const float* occ  = (const float*)d_in[1];
  const float* tokw = (const float*)d_in[2];
  const float* tokb = (const float*)d_in[3];
  const float* wq   = (const float*)d_in[4];
  const float* wk   = (const float*)d_in[5];
  const float* wvm  = (const float*)d_in[6];
  const float* wo   = (const float*)d_in[7];
  const float* ln1g = (const float*)d_in[8];
  const float* ln1b = (const float*)d_in[9];
  const float* fw1  = (const float*)d_in[10];
  const float* fb1  = (const float*)d_in[11];
  const float* fw2  = (const float*)d_in[12];
  const float* fb2  = (const float*)d_in[13];
  const float* ln2g = (const float*)d_in[14];
  const float* ln2b = (const float*)d_in[15];
  const float* fc1w = (const float*)d_in[16];
  const float* fc1b = (const float*)d_in[17];
  const float* fc2w = (const float*)d_in[18];
  const float* fc2b = (const float*)d_in[19];
  const float* fc3w = (const float*)d_in[20];
  const float* fc3b = (const float*)d_in[21];
  float* outp = (float*)d_out;

  const int ntot = in_sizes[0] / 288;     // N*V*48 / (6*48)
  const int grid = (ntot + SPB - 1) / SPB;
  hipLaunchKernelGGL(sem_kernel, dim3(grid), dim3(BLOCK), 0, stream,
                     feat, occ, tokw, tokb, wq, wk, wvm, wo,
                     ln1g, ln1b, fw1, fb1, fw2, fb2, ln2g, ln2b,
                     fc1w, fc1b, fc2w, fc2b, fc3w, fc3b, outp, ntot);
}